// Round 1
// baseline (332.363 us; speedup 1.0000x reference)
//
#include <hip/hip_runtime.h>

#define LUT_N    4096
#define DMODEL   2048
#define NTHREADS 256

__device__ __forceinline__ void lut_sincos(float theta, const float2* __restrict__ sc,
                                           float& s, float& c) {
    const float INV_TWO_PI = 0.15915494309189535f;
    const float TWO_PI_F   = 6.283185307179586f;
    const float N_OVER_2PI = 651.8986469044033f;   // LUT_N / (2*pi)
    float q    = floorf(theta * INV_TWO_PI);
    float m    = fmaf(-TWO_PI_F, q, theta);        // theta mod 2pi (may be slightly out of [0,2pi); wrap below handles it)
    float pos  = m * N_OVER_2PI;
    float i0f  = floorf(pos);
    float frac = pos - i0f;
    int i0 = ((int)i0f) & (LUT_N - 1);             // periodic wrap (handles negatives & ==LUT_N)
    int i1 = (i0 + 1) & (LUT_N - 1);
    float2 s0 = sc[i0];
    float2 s1 = sc[i1];
    s = fmaf(s1.x - s0.x, frac, s0.x);             // s0*(1-f) + s1*f
    c = fmaf(s1.y - s0.y, frac, s0.y);
}

__global__ __launch_bounds__(NTHREADS)
void liquid_echo_kernel(const float* __restrict__ x_real,
                        const float* __restrict__ x_imag,
                        const float* __restrict__ tvec,
                        const float* __restrict__ memory_real,
                        const float* __restrict__ memory_imag,
                        const float* __restrict__ w_trigger,
                        const float* __restrict__ b_trigger,
                        const float* __restrict__ w_state,
                        const float* __restrict__ b_state,
                        const float* __restrict__ kptr,
                        const float* __restrict__ sin_table,
                        const float* __restrict__ cos_table,
                        float* __restrict__ out,
                        size_t imag_off)
{
    __shared__ float2 sc[LUT_N];                   // interleaved (sin, cos): 32 KB
    __shared__ float red[NTHREADS / 64];
    __shared__ float alpha_sh;

    const int tid = threadIdx.x;
    const int row = blockIdx.x;

    // Stage LUT into LDS (tables are L2-resident across all blocks)
    #pragma unroll
    for (int i = 0; i < LUT_N / NTHREADS; ++i) {
        int idx = tid + i * NTHREADS;
        sc[idx] = make_float2(sin_table[idx], cos_table[idx]);
    }

    const float t_phi = tvec[row] * 1.6180339887498948f;   // PHI
    const int c0 = tid * 4;
    const int c1 = (DMODEL / 2) + tid * 4;
    const size_t rb = (size_t)row * DMODEL;

    // Coalesced float4 loads; x stays in registers across both phases
    float4 xr0 = *(const float4*)(x_real + rb + c0);
    float4 xr1 = *(const float4*)(x_real + rb + c1);
    float4 xi0 = *(const float4*)(x_imag + rb + c0);
    float4 xi1 = *(const float4*)(x_imag + rb + c1);
    float4 wt0 = *(const float4*)(w_trigger + c0);
    float4 wt1 = *(const float4*)(w_trigger + c1);
    float4 bt0 = *(const float4*)(b_trigger + c0);
    float4 bt1 = *(const float4*)(b_trigger + c1);

    __syncthreads();                               // LUT staged

    float xrv[8] = {xr0.x, xr0.y, xr0.z, xr0.w, xr1.x, xr1.y, xr1.z, xr1.w};
    float xiv[8] = {xi0.x, xi0.y, xi0.z, xi0.w, xi1.x, xi1.y, xi1.z, xi1.w};
    float wtv[8] = {wt0.x, wt0.y, wt0.z, wt0.w, wt1.x, wt1.y, wt1.z, wt1.w};
    float btv[8] = {bt0.x, bt0.y, bt0.z, bt0.w, bt1.x, bt1.y, bt1.z, bt1.w};

    // ---- Phase 1: trigger phase + interference partial ----
    float partial = 0.0f;
    #pragma unroll
    for (int j = 0; j < 8; ++j) {
        float wl   = 1.0f + fabsf(wtv[j]);
        float iw   = 1.0f / wl;
        float base = btv[j] + t_phi;
        float th_r = fmaf(xrv[j], iw, base);
        float th_i = fmaf(xiv[j], iw, base);
        float s_r, c_r, s_i, c_i;
        lut_sincos(th_r, sc, s_r, c_r);
        lut_sincos(th_i, sc, s_i, c_i);
        float tr = c_r * c_i - s_r * s_i;
        float ti = c_r * s_i + s_r * c_i;
        partial  = fmaf(tr, xrv[j], partial);
        partial  = fmaf(ti, xiv[j], partial);
    }

    // ---- Row reduction -> alpha ----
    #pragma unroll
    for (int off = 32; off > 0; off >>= 1)
        partial += __shfl_down(partial, off, 64);
    if ((tid & 63) == 0) red[tid >> 6] = partial;
    __syncthreads();
    if (tid == 0) {
        float tot   = red[0] + red[1] + red[2] + red[3];
        float ic    = tot / 45.254833995939045f;   // sqrt(2048)
        ic          = fminf(1.0f, fmaxf(-1.0f, ic));
        float x_inv = (1.0f - ic) * 0.5f;
        float k_eff = fabsf(kptr[0]) + 0.1f;
        alpha_sh    = expf(-k_eff * x_inv);
    }
    __syncthreads();
    const float alpha = alpha_sh;
    const float oma   = 1.0f - alpha;

    // ---- Phase 2: blend + state phase ----
    float4 mr0 = *(const float4*)(memory_real + rb + c0);
    float4 mr1 = *(const float4*)(memory_real + rb + c1);
    float4 mi0 = *(const float4*)(memory_imag + rb + c0);
    float4 mi1 = *(const float4*)(memory_imag + rb + c1);
    float4 ws0 = *(const float4*)(w_state + c0);
    float4 ws1 = *(const float4*)(w_state + c1);
    float4 bs0 = *(const float4*)(b_state + c0);
    float4 bs1 = *(const float4*)(b_state + c1);

    float mrv[8] = {mr0.x, mr0.y, mr0.z, mr0.w, mr1.x, mr1.y, mr1.z, mr1.w};
    float miv[8] = {mi0.x, mi0.y, mi0.z, mi0.w, mi1.x, mi1.y, mi1.z, mi1.w};
    float wsv[8] = {ws0.x, ws0.y, ws0.z, ws0.w, ws1.x, ws1.y, ws1.z, ws1.w};
    float bsv[8] = {bs0.x, bs0.y, bs0.z, bs0.w, bs1.x, bs1.y, bs1.z, bs1.w};

    float er[8], ei[8];
    #pragma unroll
    for (int j = 0; j < 8; ++j) {
        float br   = alpha * xrv[j] + oma * mrv[j];
        float bi   = alpha * xiv[j] + oma * miv[j];
        float wl   = 1.0f + fabsf(wsv[j]);
        float iw   = 1.0f / wl;
        float base = bsv[j] + t_phi;
        float th_r = fmaf(br, iw, base);
        float th_i = fmaf(bi, iw, base);
        float s_r, c_r, s_i, c_i;
        lut_sincos(th_r, sc, s_r, c_r);
        lut_sincos(th_i, sc, s_i, c_i);
        er[j] = c_r * c_i - s_r * s_i;
        ei[j] = c_r * s_i + s_r * c_i;
    }

    float* outr = out + rb;
    float* outi = out + imag_off + rb;
    *(float4*)(outr + c0) = make_float4(er[0], er[1], er[2], er[3]);
    *(float4*)(outr + c1) = make_float4(er[4], er[5], er[6], er[7]);
    *(float4*)(outi + c0) = make_float4(ei[0], ei[1], ei[2], ei[3]);
    *(float4*)(outi + c1) = make_float4(ei[4], ei[5], ei[6], ei[7]);
}

extern "C" void kernel_launch(void* const* d_in, const int* in_sizes, int n_in,
                              void* d_out, int out_size, void* d_ws, size_t ws_size,
                              hipStream_t stream) {
    const float* x_real      = (const float*)d_in[0];
    const float* x_imag      = (const float*)d_in[1];
    const float* t           = (const float*)d_in[2];
    const float* memory_real = (const float*)d_in[3];
    const float* memory_imag = (const float*)d_in[4];
    const float* w_trigger   = (const float*)d_in[5];
    const float* b_trigger   = (const float*)d_in[6];
    const float* w_state     = (const float*)d_in[7];
    const float* b_state     = (const float*)d_in[8];
    const float* k           = (const float*)d_in[9];
    const float* sin_table   = (const float*)d_in[10];
    const float* cos_table   = (const float*)d_in[11];
    float* out = (float*)d_out;

    int B = in_sizes[0] / DMODEL;
    size_t imag_off = (size_t)out_size / 2;

    liquid_echo_kernel<<<B, NTHREADS, 0, stream>>>(
        x_real, x_imag, t, memory_real, memory_imag,
        w_trigger, b_trigger, w_state, b_state, k,
        sin_table, cos_table, out, imag_off);
}

// Round 2
// 330.929 us; speedup vs baseline: 1.0043x; 1.0043x over previous
//
#include <hip/hip_runtime.h>

#define DMODEL   2048
#define NTHREADS 256

// sin/cos of theta (radians) via hardware v_sin_f32/v_cos_f32.
// HW takes REVOLUTIONS; fract-reduce first (exact: sin/cos periodic in 1 rev).
// Matches the reference's 4096-entry lerp LUT to ~3e-7 (LUT interp error bound
// = (2pi/4096)^2/8 = 2.9e-7; HW trig error ~1ulp). Threshold is 2e-2.
__device__ __forceinline__ void fast_sincos(float theta, float& s, float& c) {
    const float INV_TWO_PI = 0.15915494309189535f;
    float r  = theta * INV_TWO_PI;
    float rr = r - floorf(r);                 // [0,1) revolutions
#if __has_builtin(__builtin_amdgcn_sinf) && __has_builtin(__builtin_amdgcn_cosf)
    s = __builtin_amdgcn_sinf(rr);            // v_sin_f32: sin(rr*2pi)
    c = __builtin_amdgcn_cosf(rr);
#else
    s = __sinf(rr * 6.283185307179586f);
    c = __cosf(rr * 6.283185307179586f);
#endif
}

__device__ __forceinline__ float fast_rcp(float x) {
#if __has_builtin(__builtin_amdgcn_rcpf)
    return __builtin_amdgcn_rcpf(x);          // ~1e-7 rel err, plenty for 2e-2
#else
    return 1.0f / x;
#endif
}

__global__ __launch_bounds__(NTHREADS)
void liquid_echo_kernel(const float* __restrict__ x_real,
                        const float* __restrict__ x_imag,
                        const float* __restrict__ tvec,
                        const float* __restrict__ memory_real,
                        const float* __restrict__ memory_imag,
                        const float* __restrict__ w_trigger,
                        const float* __restrict__ b_trigger,
                        const float* __restrict__ w_state,
                        const float* __restrict__ b_state,
                        const float* __restrict__ kptr,
                        float* __restrict__ out,
                        size_t imag_off)
{
    __shared__ float red[NTHREADS / 64];

    const int tid = threadIdx.x;
    const int row = blockIdx.x;

    const float t_phi = tvec[row] * 1.6180339887498948f;   // PHI
    const int c0 = tid * 4;
    const int c1 = (DMODEL / 2) + tid * 4;
    const size_t rb = (size_t)row * DMODEL;

    // ---- Issue phase-1 loads (coalesced float4; x lives across both phases)
    float4 xr0 = *(const float4*)(x_real + rb + c0);
    float4 xr1 = *(const float4*)(x_real + rb + c1);
    float4 xi0 = *(const float4*)(x_imag + rb + c0);
    float4 xi1 = *(const float4*)(x_imag + rb + c1);
    float4 wt0 = *(const float4*)(w_trigger + c0);
    float4 wt1 = *(const float4*)(w_trigger + c1);
    float4 bt0 = *(const float4*)(b_trigger + c0);
    float4 bt1 = *(const float4*)(b_trigger + c1);

    float xrv[8] = {xr0.x, xr0.y, xr0.z, xr0.w, xr1.x, xr1.y, xr1.z, xr1.w};
    float xiv[8] = {xi0.x, xi0.y, xi0.z, xi0.w, xi1.x, xi1.y, xi1.z, xi1.w};
    float wtv[8] = {wt0.x, wt0.y, wt0.z, wt0.w, wt1.x, wt1.y, wt1.z, wt1.w};
    float btv[8] = {bt0.x, bt0.y, bt0.z, bt0.w, bt1.x, bt1.y, bt1.z, bt1.w};

    // ---- Phase 1: trigger via angle-sum identity
    //   trigger_real = cos(th_r + th_i), trigger_imag = sin(th_r + th_i)
    float sxy[8];                              // x_r + x_i, reused in phase 2
    float partial = 0.0f;
    #pragma unroll
    for (int j = 0; j < 8; ++j) {
        float iw   = fast_rcp(1.0f + fabsf(wtv[j]));
        float base = btv[j] + t_phi;
        sxy[j]     = xrv[j] + xiv[j];
        float ths  = fmaf(sxy[j], iw, base + base);  // th_r + th_i
        float s, c;
        fast_sincos(ths, s, c);
        partial = fmaf(c, xrv[j], partial);
        partial = fmaf(s, xiv[j], partial);
    }

    // ---- Issue phase-2 loads before the barrier (latency overlapped w/ above)
    float4 mr0 = *(const float4*)(memory_real + rb + c0);
    float4 mr1 = *(const float4*)(memory_real + rb + c1);
    float4 mi0 = *(const float4*)(memory_imag + rb + c0);
    float4 mi1 = *(const float4*)(memory_imag + rb + c1);
    float4 ws0 = *(const float4*)(w_state + c0);
    float4 ws1 = *(const float4*)(w_state + c1);
    float4 bs0 = *(const float4*)(b_state + c0);
    float4 bs1 = *(const float4*)(b_state + c1);

    // ---- Row reduction: wave shuffle -> 4 partials -> every thread finalizes
    #pragma unroll
    for (int off = 32; off > 0; off >>= 1)
        partial += __shfl_down(partial, off, 64);
    if ((tid & 63) == 0) red[tid >> 6] = partial;
    __syncthreads();

    float tot   = red[0] + red[1] + red[2] + red[3];
    float ic    = tot * (1.0f / 45.254833995939045f);      // / sqrt(2048)
    ic          = fminf(1.0f, fmaxf(-1.0f, ic));
    float x_inv = (1.0f - ic) * 0.5f;
    float k_eff = fabsf(kptr[0]) + 0.1f;
    const float alpha = __expf(-k_eff * x_inv);
    const float oma   = 1.0f - alpha;

    float mrv[8] = {mr0.x, mr0.y, mr0.z, mr0.w, mr1.x, mr1.y, mr1.z, mr1.w};
    float miv[8] = {mi0.x, mi0.y, mi0.z, mi0.w, mi1.x, mi1.y, mi1.z, mi1.w};
    float wsv[8] = {ws0.x, ws0.y, ws0.z, ws0.w, ws1.x, ws1.y, ws1.z, ws1.w};
    float bsv[8] = {bs0.x, bs0.y, bs0.z, bs0.w, bs1.x, bs1.y, bs1.z, bs1.w};

    // ---- Phase 2: blend + state phase, same identity
    float er[8], ei[8];
    #pragma unroll
    for (int j = 0; j < 8; ++j) {
        // (br + bi) = alpha*(xr+xi) + oma*(mr+mi)
        float sb   = fmaf(alpha, sxy[j], oma * (mrv[j] + miv[j]));
        float iw   = fast_rcp(1.0f + fabsf(wsv[j]));
        float base = bsv[j] + t_phi;
        float ths  = fmaf(sb, iw, base + base);            // th_sr + th_si
        float s, c;
        fast_sincos(ths, s, c);
        er[j] = c;                                          // cos(sum)
        ei[j] = s;                                          // sin(sum)
    }

    float* outr = out + rb;
    float* outi = out + imag_off + rb;
    *(float4*)(outr + c0) = make_float4(er[0], er[1], er[2], er[3]);
    *(float4*)(outr + c1) = make_float4(er[4], er[5], er[6], er[7]);
    *(float4*)(outi + c0) = make_float4(ei[0], ei[1], ei[2], ei[3]);
    *(float4*)(outi + c1) = make_float4(ei[4], ei[5], ei[6], ei[7]);
}

extern "C" void kernel_launch(void* const* d_in, const int* in_sizes, int n_in,
                              void* d_out, int out_size, void* d_ws, size_t ws_size,
                              hipStream_t stream) {
    const float* x_real      = (const float*)d_in[0];
    const float* x_imag      = (const float*)d_in[1];
    const float* t           = (const float*)d_in[2];
    const float* memory_real = (const float*)d_in[3];
    const float* memory_imag = (const float*)d_in[4];
    const float* w_trigger   = (const float*)d_in[5];
    const float* b_trigger   = (const float*)d_in[6];
    const float* w_state     = (const float*)d_in[7];
    const float* b_state     = (const float*)d_in[8];
    const float* k           = (const float*)d_in[9];
    // d_in[10], d_in[11] = sin/cos tables — superseded by HW trig (see fast_sincos)
    float* out = (float*)d_out;

    int B = in_sizes[0] / DMODEL;
    size_t imag_off = (size_t)out_size / 2;

    liquid_echo_kernel<<<B, NTHREADS, 0, stream>>>(
        x_real, x_imag, t, memory_real, memory_imag,
        w_trigger, b_trigger, w_state, b_state, k,
        out, imag_off);
}